// Round 15
// baseline (311.176 us; speedup 1.0000x reference)
//
#include <hip/hip_runtime.h>
#include <hip/hip_bf16.h>
#include <stdint.h>

typedef __attribute__((ext_vector_type(8))) __bf16 bf16x8;
typedef __attribute__((ext_vector_type(4))) float f32x4_t;
typedef __attribute__((ext_vector_type(2))) unsigned int u32x2;
typedef __attribute__((ext_vector_type(4))) unsigned int u32x4;
typedef unsigned int uint32;

#define EPSC 1e-6f

__device__ __forceinline__ unsigned short f2bf(float x){
  return __builtin_bit_cast(unsigned short, (__bf16)x);
}
__device__ __forceinline__ uint32 pk2(float a, float b){
  return (uint32)f2bf(a) | ((uint32)f2bf(b) << 16);
}
__device__ __forceinline__ float bfu2f(unsigned short u){
  return __builtin_bit_cast(float, ((uint32)u) << 16);
}

// ---------------- hdeg + prep: streaming H pass -> Hb bf16, degree partials; blocks >=1024 do WT + cnt zero ----------------
__global__ __launch_bounds__(256, 4)
void hdeg_kernel(const float* __restrict__ H, float* __restrict__ dvpart,
                 float* __restrict__ departial, unsigned short* __restrict__ Hb,
                 const float* __restrict__ W, unsigned short* __restrict__ WT,
                 int* __restrict__ cnt){
  __shared__ float wavepart[64][4];
  const int t = threadIdx.x;
  if (blockIdx.x >= 1024){
    int c = blockIdx.x - 1024;   // 0..255
    if (c == 0 && t < 128) cnt[t] = 0;
    WT[(size_t)t*256 + c] = f2bf(W[(size_t)c*256 + t]);
    return;
  }
  const int lane = t & 63;
  const int w = t >> 6;
  const int rb = blockIdx.x & 255;
  const int cb = blockIdx.x >> 8;
  const size_t colbase = (size_t)cb*1024 + t*4;
  f32x4_t dacc = {0.f, 0.f, 0.f, 0.f};
  #pragma unroll 4
  for (int r = 0; r < 64; ++r){
    const int n = rb*64 + r;
    f32x4_t v = *(const f32x4_t*)(H + (size_t)n*4096 + colbase);
    dacc[0] += v[0]; dacc[1] += v[1]; dacc[2] += v[2]; dacc[3] += v[3];
    *(u32x2*)(Hb + (size_t)n*4096 + colbase) = u32x2{pk2(v[0], v[1]), pk2(v[2], v[3])};
    float rs = (v[0] + v[1]) + (v[2] + v[3]);
    #pragma unroll
    for (int d = 1; d < 64; d <<= 1) rs += __shfl_xor(rs, d);
    if (lane == 0) wavepart[r][w] = rs;
  }
  *(f32x4_t*)(departial + (size_t)rb*4096 + cb*1024 + t*4) = dacc;
  __syncthreads();
  if (t < 64){
    float s = wavepart[t][0] + wavepart[t][1] + wavepart[t][2] + wavepart[t][3];
    dvpart[(size_t)cb*16384 + rb*64 + t] = s;
  }
}

// ---------------- small MFMA GEMM (X = emb@W path); dvs computed in-block from dvpart ----------------
template<int LDA, int KB, int NMT, int CHUNK>
__global__ __launch_bounds__(256, 2)
void gemm_x(const float* __restrict__ Af, const unsigned short* __restrict__ BT,
            const float* __restrict__ dvpart, unsigned short* __restrict__ XsT)
{
  constexpr int NIT = CHUNK / 32;
  constexpr int ASZ = 64*32*2;
  constexpr int BSZ = 256*32*2;
  __shared__ __align__(16) char lds[2*ASZ + 2*BSZ];
  __shared__ float dvls[64];

  const int t = threadIdx.x;
  const int lane = t & 63;
  const int w = t >> 6;
  const int mt = blockIdx.x % NMT;
  const int s  = blockIdx.x / NMT;
  const int k0 = s * CHUNK;

  const int st_r  = t >> 2, st_cq = t & 3;

  f32x4_t acc[4][4] = {};
  f32x4_t pa[2];

  auto loadA = [&](int it){
    const float* p = Af + (size_t)(mt*64 + st_r)*LDA + k0 + it*32 + st_cq*4;
    pa[0] = *(const f32x4_t*)(p);
    pa[1] = *(const f32x4_t*)(p + 16);
  };

  auto gllB = [&](int it, int buf){
    char* bb = lds + 2*ASZ + buf*BSZ;
    const int kcur = k0 + it*32;
    const int swzh = ((lane & 3) ^ ((lane >> 2) & 3)) << 3;
    #pragma unroll
    for (int j = 0; j < 4; ++j){
      int chunk = w*4 + j;
      int frow = chunk*16 + (lane >> 2);
      const unsigned short* src = BT + (size_t)frow*KB + kcur + swzh;
      __builtin_amdgcn_global_load_lds((const __attribute__((address_space(1))) void*)src,
                                       (__attribute__((address_space(3))) void*)(bb + chunk*1024),
                                       16, 0, 0);
    }
  };

  auto stageA = [&](int buf){
    char* ab = lds + buf*ASZ;
    #pragma unroll
    for (int i = 0; i < 2; ++i){
      int f4 = st_cq + 4*i;
      uint32 lo = pk2(pa[i][0], pa[i][1]);
      uint32 hi = pk2(pa[i][2], pa[i][3]);
      *(u32x2*)(ab + st_r*64 + ((f4*8) ^ ((st_r & 3) << 4))) = u32x2{lo, hi};
    }
  };

  auto compute = [&](int buf){
    const char* ab = lds + buf*ASZ;
    const char* bb = lds + 2*ASZ + buf*BSZ;
    const int kswz = (((lane >> 4) ^ (lane & 3)) << 4);
    bf16x8 af[4], bfr[4];
    #pragma unroll
    for (int mi = 0; mi < 4; ++mi){
      int row = mi*16 + (lane & 15);
      af[mi] = *(const bf16x8*)(ab + row*64 + kswz);
    }
    #pragma unroll
    for (int fi = 0; fi < 4; ++fi){
      int row = w*64 + fi*16 + (lane & 15);
      bfr[fi] = *(const bf16x8*)(bb + row*64 + kswz);
    }
    #pragma unroll
    for (int mi = 0; mi < 4; ++mi){
      #pragma unroll
      for (int fi = 0; fi < 4; ++fi){
        acc[mi][fi] = __builtin_amdgcn_mfma_f32_16x16x32_bf16(af[mi], bfr[fi], acc[mi][fi], 0, 0, 0);
      }
    }
  };

  // block-local dvs (same add order as original finish_deg -> bit-identical)
  if (t < 64){
    int n = mt*64 + t;
    float s0 = dvpart[n] + dvpart[16384 + n] + dvpart[2*16384 + n] + dvpart[3*16384 + n];
    dvls[t] = rsqrtf(s0 + EPSC);
  }

  loadA(0);
  gllB(0, 0);
  stageA(0);
  __syncthreads();

  int cur = 0;
  #pragma unroll 1
  for (int it = 0; it < NIT; ++it){
    if (it + 1 < NIT){
      loadA(it + 1);
      gllB(it + 1, cur ^ 1);
    }
    compute(cur);
    if (it + 1 < NIT) stageA(cur ^ 1);
    __syncthreads();
    cur ^= 1;
  }

  #pragma unroll
  for (int mi = 0; mi < 4; ++mi){
    int l0 = mi*16 + ((lane >> 4) * 4);
    int n0 = mt*64 + l0;
    float d0 = dvls[l0], d1 = dvls[l0+1], d2 = dvls[l0+2], d3 = dvls[l0+3];
    #pragma unroll
    for (int fi = 0; fi < 4; ++fi){
      int f = w*64 + fi*16 + (lane & 15);
      uint32 lo = pk2(acc[mi][fi][0]*d0, acc[mi][fi][1]*d1);
      uint32 hi = pk2(acc[mi][fi][2]*d2, acc[mi][fi][3]*d3);
      *(u32x2*)(XsT + (size_t)f*16384 + n0) = u32x2{lo, hi};
    }
  }
}

// ---------------- big MFMA GEMM BM=128 x BN=256, 512 thr (R10 pipeline, verified) ----------------
// BK=64 phases, 3-tile LDS pipeline, issue-2-tiles-ahead, counted vmcnt(6), bf16 partial output.
// EPIL=1 (GEMM2): last-arrival block per mt performs the fin pass (relu(dvs*(P0+P1)) -> f32 out).
template<int TRANS, int EPIL, int LDA, int KB, int NMT, int CHUNK>
__global__ __launch_bounds__(512, 1)
void gemm_h(const unsigned short* __restrict__ Ah, const unsigned short* __restrict__ BT,
            unsigned short* __restrict__ Cp, int* __restrict__ cnt,
            const float* __restrict__ dvpart, float* __restrict__ outp)
{
  constexpr int NIT = CHUNK / 32;   // slices
  constexpr int NT  = NIT / 2;      // BK=64 tiles
  static_assert(NT % 2 == 0 && NT >= 4, "tail/unroll assumptions");
  constexpr int ASLICE = 128*32*2;
  constexpr int BSLICE = 256*32*2;
  constexpr int ATILE = 2*ASLICE;
  constexpr int BTILE = 2*BSLICE;
  __shared__ __align__(16) char lds[3*ATILE + 3*BTILE];  // 147456 B
  __shared__ int smret;

  const int t = threadIdx.x;
  const int lane = t & 63;
  const int w = t >> 6;
  const int wm = w >> 2;
  const int wf = w & 3;
  const int mt = blockIdx.x % NMT;
  const int s  = blockIdx.x / NMT;
  const int k0 = s * CHUNK;

  f32x4_t acc[4][4] = {};

  auto abase = [&](int sl){ return ((sl >> 1) % 3)*ATILE + (sl & 1)*ASLICE; };
  auto bbase = [&](int sl){ return 3*ATILE + ((sl >> 1) % 3)*BTILE + (sl & 1)*BSLICE; };

  auto gllB = [&](int sl){
    char* bb = lds + bbase(sl);
    const int kcur = k0 + sl*32;
    const int swzh = ((lane & 3) ^ ((lane >> 2) & 3)) << 3;
    #pragma unroll
    for (int j = 0; j < 2; ++j){
      int chunk = w*2 + j;
      int frow = chunk*16 + (lane >> 2);
      const unsigned short* src = BT + (size_t)frow*KB + kcur + swzh;
      __builtin_amdgcn_global_load_lds((const __attribute__((address_space(1))) void*)src,
                                       (__attribute__((address_space(3))) void*)(bb + chunk*1024),
                                       16, 0, 0);
    }
  };

  auto gllA = [&](int sl){
    char* ab = lds + abase(sl);
    const int kcur = k0 + sl*32;
    const int arow = lane >> 2;
    const int kqs  = (lane & 3) ^ (arow & 3);
    const unsigned short* src = Ah + (size_t)(mt*128 + w*16 + arow)*LDA + kcur + kqs*8;
    __builtin_amdgcn_global_load_lds((const __attribute__((address_space(1))) void*)src,
                                     (__attribute__((address_space(3))) void*)(ab + w*1024),
                                     16, 0, 0);
  };

  auto loadA_tr = [&](int sl) -> u32x4 {
    return *(const u32x4*)(Ah + (size_t)(k0 + sl*32 + (t >> 4))*LDA + mt*128 + (t & 15)*8);
  };

  auto stageA_tr = [&](int sl, u32x4 paw){
    char* ab = lds + abase(sl);
    const int n = t >> 4;
    const int trq = t & 15;
    const bool odd = n & 1;
    const int np = n >> 1;
    uint32 pw[4];
    #pragma unroll
    for (int j = 0; j < 4; ++j) pw[j] = (uint32)__shfl_xor((int)paw[j], 16);
    #pragma unroll
    for (int j = 0; j < 4; ++j){
      int e = trq*8 + 2*j + (odd ? 1 : 0);
      uint32 word = odd ? ((pw[j] >> 16)      | (paw[j] & 0xFFFF0000u))
                        : ((paw[j] & 0xFFFFu) | (pw[j] << 16));
      int pq = (np >> 2) ^ (trq & 3);
      *(uint32*)(ab + e*64 + pq*16 + (np & 3)*4) = word;
    }
  };

  auto compute = [&](int sl){
    const char* ab = lds + abase(sl);
    const char* bb = lds + bbase(sl);
    const int l15 = lane & 15;
    const int kq = lane >> 4;
    bf16x8 af[4], bfr[4];
    #pragma unroll
    for (int mi = 0; mi < 4; ++mi){
      int row = wm*64 + mi*16 + l15;
      int q = TRANS ? (kq ^ ((row >> 3) & 3)) : (kq ^ (row & 3));
      af[mi] = *(const bf16x8*)(ab + row*64 + q*16);
    }
    #pragma unroll
    for (int fi = 0; fi < 4; ++fi){
      int row = wf*64 + fi*16 + l15;
      bfr[fi] = *(const bf16x8*)(bb + row*64 + ((kq ^ (l15 & 3)) << 4));
    }
    #pragma unroll
    for (int mi = 0; mi < 4; ++mi){
      #pragma unroll
      for (int fi = 0; fi < 4; ++fi){
        acc[mi][fi] = __builtin_amdgcn_mfma_f32_16x16x32_bf16(af[mi], bfr[fi], acc[mi][fi], 0, 0, 0);
      }
    }
  };

  if (TRANS){
    u32x4 e0, e1, o0, o1;
    e0 = loadA_tr(0); e1 = loadA_tr(1); gllB(0); gllB(1);
    o0 = loadA_tr(2); o1 = loadA_tr(3); gllB(2); gllB(3);
    stageA_tr(0, e0); stageA_tr(1, e1);
    asm volatile("s_waitcnt vmcnt(6) lgkmcnt(0)" ::: "memory");
    __builtin_amdgcn_s_barrier();

    #pragma unroll 1
    for (int T = 0; T < NT - 2; T += 2){
      e0 = loadA_tr(2*T + 4); e1 = loadA_tr(2*T + 5);
      gllB(2*T + 4); gllB(2*T + 5);
      compute(2*T); compute(2*T + 1);
      stageA_tr(2*T + 2, o0); stageA_tr(2*T + 3, o1);
      asm volatile("s_waitcnt vmcnt(6) lgkmcnt(0)" ::: "memory");
      __builtin_amdgcn_s_barrier();
      o0 = loadA_tr(2*T + 6); o1 = loadA_tr(2*T + 7);
      gllB(2*T + 6); gllB(2*T + 7);
      compute(2*T + 2); compute(2*T + 3);
      stageA_tr(2*T + 4, e0); stageA_tr(2*T + 5, e1);
      asm volatile("s_waitcnt vmcnt(6) lgkmcnt(0)" ::: "memory");
      __builtin_amdgcn_s_barrier();
    }
    compute(2*NT - 4); compute(2*NT - 3);
    stageA_tr(2*NT - 2, o0); stageA_tr(2*NT - 1, o1);
    asm volatile("s_waitcnt vmcnt(0) lgkmcnt(0)" ::: "memory");
    __builtin_amdgcn_s_barrier();
    compute(2*NT - 2); compute(2*NT - 1);
  } else {
    gllB(0); gllA(0); gllB(1); gllA(1);
    gllB(2); gllA(2); gllB(3); gllA(3);
    asm volatile("s_waitcnt vmcnt(6)" ::: "memory");
    __builtin_amdgcn_s_barrier();

    #pragma unroll 1
    for (int T = 0; T < NT - 2; ++T){
      gllB(2*T + 4); gllA(2*T + 4); gllB(2*T + 5); gllA(2*T + 5);
      compute(2*T); compute(2*T + 1);
      asm volatile("s_waitcnt vmcnt(6)" ::: "memory");
      __builtin_amdgcn_s_barrier();
    }
    compute(2*NT - 4); compute(2*NT - 3);
    asm volatile("s_waitcnt vmcnt(0)" ::: "memory");
    __builtin_amdgcn_s_barrier();
    compute(2*NT - 2); compute(2*NT - 1);
  }

  unsigned short* C = Cp + (size_t)s * (NMT*128) * 256;
  #pragma unroll
  for (int mi = 0; mi < 4; ++mi){
    int row0 = mt*128 + wm*64 + mi*16 + ((lane >> 4) * 4);
    #pragma unroll
    for (int fi = 0; fi < 4; ++fi){
      int f = wf*64 + fi*16 + (lane & 15);
      #pragma unroll
      for (int r = 0; r < 4; ++r)
        C[(size_t)(row0 + r)*256 + f] = f2bf(acc[mi][fi][r]);
    }
  }

  if (EPIL == 1){
    // last-arrival fin: relu(dvs[n] * (P0+P1)) -> f32 out, for this mt's 128 rows
    __threadfence();
    __syncthreads();
    if (t == 0) smret = atomicAdd(cnt + mt, 1);
    __syncthreads();
    if (smret == 1){
      __threadfence();
      #pragma unroll 1
      for (int u = 0; u < 8; ++u){
        int gidx = t + u*512;
        int nl = gidx >> 5;
        int f0 = (gidx & 31) * 8;
        int n = mt*128 + nl;
        size_t off = (size_t)n*256 + f0;
        u32x4 a = *(const u32x4*)(Cp + off);
        u32x4 b = *(const u32x4*)(Cp + (size_t)16384*256 + off);
        float ssum = dvpart[n] + dvpart[16384 + n] + dvpart[2*16384 + n] + dvpart[3*16384 + n];
        float d = rsqrtf(ssum + EPSC);
        f32x4_t o1, o2;
        #pragma unroll
        for (int j = 0; j < 4; ++j){
          float alo = __builtin_bit_cast(float, a[j] << 16);
          float ahi = __builtin_bit_cast(float, a[j] & 0xFFFF0000u);
          float blo = __builtin_bit_cast(float, b[j] << 16);
          float bhi = __builtin_bit_cast(float, b[j] & 0xFFFF0000u);
          float lo = fmaxf((alo + blo) * d, 0.f);
          float hi = fmaxf((ahi + bhi) * d, 0.f);
          if (j < 2){ o1[2*j] = lo; o1[2*j + 1] = hi; }
          else      { o2[2*(j-2)] = lo; o2[2*(j-2) + 1] = hi; }
        }
        *(f32x4_t*)(outp + off) = o1;
        *(f32x4_t*)(outp + off + 4) = o2;
      }
    }
  }
}

// ---------------- mid: de computed in-block from departial (original finish_deg add order) ----------------
__global__ void mid_kernel(const unsigned short* __restrict__ T1p, const float* __restrict__ departial,
                           unsigned short* __restrict__ T1sT){
  __shared__ float sm[4][4];       // [r][part]
  __shared__ float de_local[4];
  int t = threadIdx.x;
  int e0 = blockIdx.x * 4;
  if (t < 16){
    int r = t & 3, part = t >> 2;
    float s = 0.f;
    #pragma unroll 4
    for (int i = 0; i < 64; ++i)
      s += departial[(size_t)(part*64 + i)*4096 + e0 + r];
    sm[r][part] = s;
  }
  __syncthreads();
  if (t < 4) de_local[t] = sm[t][0] + sm[t][1] + sm[t][2] + sm[t][3];
  __syncthreads();
  int f = t;
  float v[4];
  #pragma unroll
  for (int r = 0; r < 4; ++r){
    float acc = 0.f;
    #pragma unroll
    for (int s = 0; s < 8; ++s)
      acc += bfu2f(T1p[(size_t)s*4096*256 + (size_t)(e0 + r)*256 + f]);
    v[r] = acc / (de_local[r] + EPSC);
  }
  uint32 lo = pk2(v[0], v[1]);
  uint32 hi = pk2(v[2], v[3]);
  *(u32x2*)(T1sT + (size_t)f*4096 + e0) = u32x2{lo, hi};
}

extern "C" void kernel_launch(void* const* d_in, const int* in_sizes, int n_in,
                              void* d_out, int out_size, void* d_ws, size_t ws_size,
                              hipStream_t stream) {
  const float* emb = (const float*)d_in[0];   // [16384,256]
  const float* H   = (const float*)d_in[1];   // [16384,4096]
  const float* W   = (const float*)d_in[2];   // [256,256]
  float* out = (float*)d_out;                 // f32 [16384,256]

  char* ws = (char*)d_ws;
  unsigned short* WT        = (unsigned short*)(ws + 0);         //  131072 B
  unsigned short* XsT       = (unsigned short*)(ws + 131072);    // 8388608 B  [256][16384] bf16
  unsigned short* T1sT      = (unsigned short*)(ws + 8519680);   // 2097152 B  [256][4096] bf16
  unsigned short* Hb        = (unsigned short*)(ws + 10616832);  // 134217728 B [16384][4096] bf16
  unsigned short* T1p16     = (unsigned short*)(ws + 144834560); // 16777216 B [8][4096][256] bf16
  unsigned short* Op16      = (unsigned short*)(ws + 161611776); // 16777216 B [2][16384][256] bf16
  float*          departial = (float*)(ws + 178388992);          // 4194304 B [256][4096]
  float*          dvpart    = (float*)(ws + 182583296);          // 262144 B [4][16384]
  int*            cnt       = (int*)(ws + 182845440);            // 512 B (fin counters, zeroed each call)
  // total ws usage: 182,845,952 B

  // single streaming pass over H: Hb + degree partials; blocks 1024..1279 build WT + zero cnt
  hdeg_kernel<<<1280, 256, 0, stream>>>(H, dvpart, departial, Hb, W, WT, cnt);

  // X: XsT[f][n] = bf16(dvs[n] * (emb@W)[n][f]);  M=16384, K=256  (dvs from dvpart in-block)
  gemm_x<256, 256, 256, 256><<<256, 256, 0, stream>>>(emb, WT, dvpart, XsT);

  // GEMM1: T1p16[s][e][f];  M=4096 (e), K=16384 (n), split-K=8
  gemm_h<1, 0, 4096, 16384, 32, 2048><<<256, 512, 0, stream>>>(Hb, XsT, T1p16, nullptr, nullptr, nullptr);

  // T1s = De^-1 * sum(T1p16), bf16 transposed  (de from departial in-block)
  mid_kernel<<<1024, 256, 0, stream>>>(T1p16, departial, T1sT);

  // GEMM2: Op16[s][n][f];  M=16384 (n), K=4096 (e), split-K=2; last-arrival block per mt does fin -> out
  gemm_h<0, 1, 4096, 4096, 128, 2048><<<256, 512, 0, stream>>>(Hb, T1sT, Op16, cnt, dvpart, out);
}

// Round 16
// 206.686 us; speedup vs baseline: 1.5055x; 1.5055x over previous
//
#include <hip/hip_runtime.h>
#include <hip/hip_bf16.h>
#include <stdint.h>

typedef __attribute__((ext_vector_type(8))) __bf16 bf16x8;
typedef __attribute__((ext_vector_type(4))) float f32x4_t;
typedef __attribute__((ext_vector_type(2))) unsigned int u32x2;
typedef __attribute__((ext_vector_type(4))) unsigned int u32x4;
typedef unsigned int uint32;

#define EPSC 1e-6f

__device__ __forceinline__ unsigned short f2bf(float x){
  return __builtin_bit_cast(unsigned short, (__bf16)x);
}
__device__ __forceinline__ uint32 pk2(float a, float b){
  return (uint32)f2bf(a) | ((uint32)f2bf(b) << 16);
}
__device__ __forceinline__ float bfu2f(unsigned short u){
  return __builtin_bit_cast(float, ((uint32)u) << 16);
}

// ---------------- hdeg + prep: streaming H pass -> Hb bf16, degree partials; blocks >=1024 do WT ----------------
// grid 1280: blocks 0..1023 = (rb 0..255) x (cb 0..3), 64 rows x 1024 cols each; blocks 1024..1279: WT[f][c]=bf16(W[c][f])
__global__ __launch_bounds__(256, 4)
void hdeg_kernel(const float* __restrict__ H, float* __restrict__ dvpart,
                 float* __restrict__ departial, unsigned short* __restrict__ Hb,
                 const float* __restrict__ W, unsigned short* __restrict__ WT){
  __shared__ float wavepart[64][4];
  const int t = threadIdx.x;
  if (blockIdx.x >= 1024){
    int c = blockIdx.x - 1024;   // 0..255
    WT[(size_t)t*256 + c] = f2bf(W[(size_t)c*256 + t]);
    return;
  }
  const int lane = t & 63;
  const int w = t >> 6;
  const int rb = blockIdx.x & 255;
  const int cb = blockIdx.x >> 8;
  const size_t colbase = (size_t)cb*1024 + t*4;
  f32x4_t dacc = {0.f, 0.f, 0.f, 0.f};
  #pragma unroll 4
  for (int r = 0; r < 64; ++r){
    const int n = rb*64 + r;
    f32x4_t v = *(const f32x4_t*)(H + (size_t)n*4096 + colbase);
    dacc[0] += v[0]; dacc[1] += v[1]; dacc[2] += v[2]; dacc[3] += v[3];
    *(u32x2*)(Hb + (size_t)n*4096 + colbase) = u32x2{pk2(v[0], v[1]), pk2(v[2], v[3])};
    float rs = (v[0] + v[1]) + (v[2] + v[3]);
    #pragma unroll
    for (int d = 1; d < 64; d <<= 1) rs += __shfl_xor(rs, d);
    if (lane == 0) wavepart[r][w] = rs;
  }
  *(f32x4_t*)(departial + (size_t)rb*4096 + cb*1024 + t*4) = dacc;
  __syncthreads();
  if (t < 64){
    float s = wavepart[t][0] + wavepart[t][1] + wavepart[t][2] + wavepart[t][3];
    dvpart[(size_t)cb*16384 + rb*64 + t] = s;
  }
}

// ---------------- small MFMA GEMM (X = emb@W path); dvs computed in-block from dvpart ----------------
template<int LDA, int KB, int NMT, int CHUNK>
__global__ __launch_bounds__(256, 2)
void gemm_x(const float* __restrict__ Af, const unsigned short* __restrict__ BT,
            const float* __restrict__ dvpart, unsigned short* __restrict__ XsT)
{
  constexpr int NIT = CHUNK / 32;
  constexpr int ASZ = 64*32*2;
  constexpr int BSZ = 256*32*2;
  __shared__ __align__(16) char lds[2*ASZ + 2*BSZ];
  __shared__ float dvls[64];

  const int t = threadIdx.x;
  const int lane = t & 63;
  const int w = t >> 6;
  const int mt = blockIdx.x % NMT;
  const int s  = blockIdx.x / NMT;
  const int k0 = s * CHUNK;

  const int st_r  = t >> 2, st_cq = t & 3;

  f32x4_t acc[4][4] = {};
  f32x4_t pa[2];

  auto loadA = [&](int it){
    const float* p = Af + (size_t)(mt*64 + st_r)*LDA + k0 + it*32 + st_cq*4;
    pa[0] = *(const f32x4_t*)(p);
    pa[1] = *(const f32x4_t*)(p + 16);
  };

  auto gllB = [&](int it, int buf){
    char* bb = lds + 2*ASZ + buf*BSZ;
    const int kcur = k0 + it*32;
    const int swzh = ((lane & 3) ^ ((lane >> 2) & 3)) << 3;
    #pragma unroll
    for (int j = 0; j < 4; ++j){
      int chunk = w*4 + j;
      int frow = chunk*16 + (lane >> 2);
      const unsigned short* src = BT + (size_t)frow*KB + kcur + swzh;
      __builtin_amdgcn_global_load_lds((const __attribute__((address_space(1))) void*)src,
                                       (__attribute__((address_space(3))) void*)(bb + chunk*1024),
                                       16, 0, 0);
    }
  };

  auto stageA = [&](int buf){
    char* ab = lds + buf*ASZ;
    #pragma unroll
    for (int i = 0; i < 2; ++i){
      int f4 = st_cq + 4*i;
      uint32 lo = pk2(pa[i][0], pa[i][1]);
      uint32 hi = pk2(pa[i][2], pa[i][3]);
      *(u32x2*)(ab + st_r*64 + ((f4*8) ^ ((st_r & 3) << 4))) = u32x2{lo, hi};
    }
  };

  auto compute = [&](int buf){
    const char* ab = lds + buf*ASZ;
    const char* bb = lds + 2*ASZ + buf*BSZ;
    const int kswz = (((lane >> 4) ^ (lane & 3)) << 4);
    bf16x8 af[4], bfr[4];
    #pragma unroll
    for (int mi = 0; mi < 4; ++mi){
      int row = mi*16 + (lane & 15);
      af[mi] = *(const bf16x8*)(ab + row*64 + kswz);
    }
    #pragma unroll
    for (int fi = 0; fi < 4; ++fi){
      int row = w*64 + fi*16 + (lane & 15);
      bfr[fi] = *(const bf16x8*)(bb + row*64 + kswz);
    }
    #pragma unroll
    for (int mi = 0; mi < 4; ++mi){
      #pragma unroll
      for (int fi = 0; fi < 4; ++fi){
        acc[mi][fi] = __builtin_amdgcn_mfma_f32_16x16x32_bf16(af[mi], bfr[fi], acc[mi][fi], 0, 0, 0);
      }
    }
  };

  // block-local dvs (same add order as old finish_deg -> bit-identical)
  if (t < 64){
    int n = mt*64 + t;
    float s0 = dvpart[n] + dvpart[16384 + n] + dvpart[2*16384 + n] + dvpart[3*16384 + n];
    dvls[t] = rsqrtf(s0 + EPSC);
  }

  loadA(0);
  gllB(0, 0);
  stageA(0);
  __syncthreads();

  int cur = 0;
  #pragma unroll 1
  for (int it = 0; it < NIT; ++it){
    if (it + 1 < NIT){
      loadA(it + 1);
      gllB(it + 1, cur ^ 1);
    }
    compute(cur);
    if (it + 1 < NIT) stageA(cur ^ 1);
    __syncthreads();
    cur ^= 1;
  }

  #pragma unroll
  for (int mi = 0; mi < 4; ++mi){
    int l0 = mi*16 + ((lane >> 4) * 4);
    int n0 = mt*64 + l0;
    float d0 = dvls[l0], d1 = dvls[l0+1], d2 = dvls[l0+2], d3 = dvls[l0+3];
    #pragma unroll
    for (int fi = 0; fi < 4; ++fi){
      int f = w*64 + fi*16 + (lane & 15);
      uint32 lo = pk2(acc[mi][fi][0]*d0, acc[mi][fi][1]*d1);
      uint32 hi = pk2(acc[mi][fi][2]*d2, acc[mi][fi][3]*d3);
      *(u32x2*)(XsT + (size_t)f*16384 + n0) = u32x2{lo, hi};
    }
  }
}

// ---------------- big MFMA GEMM BM=128 x BN=256, 512 thr (R10 exact) ----------------
// BK=64 phases, 3-tile LDS pipeline, issue-2-tiles-ahead, counted vmcnt(6), bf16 partial output.
template<int TRANS, int LDA, int KB, int NMT, int CHUNK>
__global__ __launch_bounds__(512, 1)
void gemm_h(const unsigned short* __restrict__ Ah, const unsigned short* __restrict__ BT,
            unsigned short* __restrict__ Cp)
{
  constexpr int NIT = CHUNK / 32;   // slices
  constexpr int NT  = NIT / 2;      // BK=64 tiles
  static_assert(NT % 2 == 0 && NT >= 4, "tail/unroll assumptions");
  constexpr int ASLICE = 128*32*2;
  constexpr int BSLICE = 256*32*2;
  constexpr int ATILE = 2*ASLICE;
  constexpr int BTILE = 2*BSLICE;
  __shared__ __align__(16) char lds[3*ATILE + 3*BTILE];  // 147456 B

  const int t = threadIdx.x;
  const int lane = t & 63;
  const int w = t >> 6;
  const int wm = w >> 2;
  const int wf = w & 3;
  const int mt = blockIdx.x % NMT;
  const int s  = blockIdx.x / NMT;
  const int k0 = s * CHUNK;

  f32x4_t acc[4][4] = {};

  auto abase = [&](int sl){ return ((sl >> 1) % 3)*ATILE + (sl & 1)*ASLICE; };
  auto bbase = [&](int sl){ return 3*ATILE + ((sl >> 1) % 3)*BTILE + (sl & 1)*BSLICE; };

  auto gllB = [&](int sl){
    char* bb = lds + bbase(sl);
    const int kcur = k0 + sl*32;
    const int swzh = ((lane & 3) ^ ((lane >> 2) & 3)) << 3;
    #pragma unroll
    for (int j = 0; j < 2; ++j){
      int chunk = w*2 + j;
      int frow = chunk*16 + (lane >> 2);
      const unsigned short* src = BT + (size_t)frow*KB + kcur + swzh;
      __builtin_amdgcn_global_load_lds((const __attribute__((address_space(1))) void*)src,
                                       (__attribute__((address_space(3))) void*)(bb + chunk*1024),
                                       16, 0, 0);
    }
  };

  auto gllA = [&](int sl){
    char* ab = lds + abase(sl);
    const int kcur = k0 + sl*32;
    const int arow = lane >> 2;
    const int kqs  = (lane & 3) ^ (arow & 3);
    const unsigned short* src = Ah + (size_t)(mt*128 + w*16 + arow)*LDA + kcur + kqs*8;
    __builtin_amdgcn_global_load_lds((const __attribute__((address_space(1))) void*)src,
                                     (__attribute__((address_space(3))) void*)(ab + w*1024),
                                     16, 0, 0);
  };

  auto loadA_tr = [&](int sl) -> u32x4 {
    return *(const u32x4*)(Ah + (size_t)(k0 + sl*32 + (t >> 4))*LDA + mt*128 + (t & 15)*8);
  };

  auto stageA_tr = [&](int sl, u32x4 paw){
    char* ab = lds + abase(sl);
    const int n = t >> 4;
    const int trq = t & 15;
    const bool odd = n & 1;
    const int np = n >> 1;
    uint32 pw[4];
    #pragma unroll
    for (int j = 0; j < 4; ++j) pw[j] = (uint32)__shfl_xor((int)paw[j], 16);
    #pragma unroll
    for (int j = 0; j < 4; ++j){
      int e = trq*8 + 2*j + (odd ? 1 : 0);
      uint32 word = odd ? ((pw[j] >> 16)      | (paw[j] & 0xFFFF0000u))
                        : ((paw[j] & 0xFFFFu) | (pw[j] << 16));
      int pq = (np >> 2) ^ (trq & 3);
      *(uint32*)(ab + e*64 + pq*16 + (np & 3)*4) = word;
    }
  };

  auto compute = [&](int sl){
    const char* ab = lds + abase(sl);
    const char* bb = lds + bbase(sl);
    const int l15 = lane & 15;
    const int kq = lane >> 4;
    bf16x8 af[4], bfr[4];
    #pragma unroll
    for (int mi = 0; mi < 4; ++mi){
      int row = wm*64 + mi*16 + l15;
      int q = TRANS ? (kq ^ ((row >> 3) & 3)) : (kq ^ (row & 3));
      af[mi] = *(const bf16x8*)(ab + row*64 + q*16);
    }
    #pragma unroll
    for (int fi = 0; fi < 4; ++fi){
      int row = wf*64 + fi*16 + l15;
      bfr[fi] = *(const bf16x8*)(bb + row*64 + ((kq ^ (l15 & 3)) << 4));
    }
    #pragma unroll
    for (int mi = 0; mi < 4; ++mi){
      #pragma unroll
      for (int fi = 0; fi < 4; ++fi){
        acc[mi][fi] = __builtin_amdgcn_mfma_f32_16x16x32_bf16(af[mi], bfr[fi], acc[mi][fi], 0, 0, 0);
      }
    }
  };

  if (TRANS){
    u32x4 e0, e1, o0, o1;
    e0 = loadA_tr(0); e1 = loadA_tr(1); gllB(0); gllB(1);
    o0 = loadA_tr(2); o1 = loadA_tr(3); gllB(2); gllB(3);
    stageA_tr(0, e0); stageA_tr(1, e1);
    asm volatile("s_waitcnt vmcnt(6) lgkmcnt(0)" ::: "memory");
    __builtin_amdgcn_s_barrier();

    #pragma unroll 1
    for (int T = 0; T < NT - 2; T += 2){
      e0 = loadA_tr(2*T + 4); e1 = loadA_tr(2*T + 5);
      gllB(2*T + 4); gllB(2*T + 5);
      compute(2*T); compute(2*T + 1);
      stageA_tr(2*T + 2, o0); stageA_tr(2*T + 3, o1);
      asm volatile("s_waitcnt vmcnt(6) lgkmcnt(0)" ::: "memory");
      __builtin_amdgcn_s_barrier();
      o0 = loadA_tr(2*T + 6); o1 = loadA_tr(2*T + 7);
      gllB(2*T + 6); gllB(2*T + 7);
      compute(2*T + 2); compute(2*T + 3);
      stageA_tr(2*T + 4, e0); stageA_tr(2*T + 5, e1);
      asm volatile("s_waitcnt vmcnt(6) lgkmcnt(0)" ::: "memory");
      __builtin_amdgcn_s_barrier();
    }
    compute(2*NT - 4); compute(2*NT - 3);
    stageA_tr(2*NT - 2, o0); stageA_tr(2*NT - 1, o1);
    asm volatile("s_waitcnt vmcnt(0) lgkmcnt(0)" ::: "memory");
    __builtin_amdgcn_s_barrier();
    compute(2*NT - 2); compute(2*NT - 1);
  } else {
    gllB(0); gllA(0); gllB(1); gllA(1);
    gllB(2); gllA(2); gllB(3); gllA(3);
    asm volatile("s_waitcnt vmcnt(6)" ::: "memory");
    __builtin_amdgcn_s_barrier();

    #pragma unroll 1
    for (int T = 0; T < NT - 2; ++T){
      gllB(2*T + 4); gllA(2*T + 4); gllB(2*T + 5); gllA(2*T + 5);
      compute(2*T); compute(2*T + 1);
      asm volatile("s_waitcnt vmcnt(6)" ::: "memory");
      __builtin_amdgcn_s_barrier();
    }
    compute(2*NT - 4); compute(2*NT - 3);
    asm volatile("s_waitcnt vmcnt(0)" ::: "memory");
    __builtin_amdgcn_s_barrier();
    compute(2*NT - 2); compute(2*NT - 1);
  }

  unsigned short* C = Cp + (size_t)s * (NMT*128) * 256;
  #pragma unroll
  for (int mi = 0; mi < 4; ++mi){
    int row0 = mt*128 + wm*64 + mi*16 + ((lane >> 4) * 4);
    #pragma unroll
    for (int fi = 0; fi < 4; ++fi){
      int f = wf*64 + fi*16 + (lane & 15);
      #pragma unroll
      for (int r = 0; r < 4; ++r)
        C[(size_t)(row0 + r)*256 + f] = f2bf(acc[mi][fi][r]);
    }
  }
}

// ---------------- mid: de computed in-block from departial (finish_deg's exact add order) ----------------
__global__ void mid_kernel(const unsigned short* __restrict__ T1p, const float* __restrict__ departial,
                           unsigned short* __restrict__ T1sT){
  __shared__ float sm[4][4];       // [r][part]
  __shared__ float de_local[4];
  int t = threadIdx.x;
  int e0 = blockIdx.x * 4;
  if (t < 16){
    int r = t & 3, part = t >> 2;
    float s = 0.f;
    #pragma unroll 4
    for (int i = 0; i < 64; ++i)
      s += departial[(size_t)(part*64 + i)*4096 + e0 + r];
    sm[r][part] = s;
  }
  __syncthreads();
  if (t < 4) de_local[t] = sm[t][0] + sm[t][1] + sm[t][2] + sm[t][3];
  __syncthreads();
  int f = t;
  float v[4];
  #pragma unroll
  for (int r = 0; r < 4; ++r){
    float acc = 0.f;
    #pragma unroll
    for (int s = 0; s < 8; ++s)
      acc += bfu2f(T1p[(size_t)s*4096*256 + (size_t)(e0 + r)*256 + f]);
    v[r] = acc / (de_local[r] + EPSC);
  }
  uint32 lo = pk2(v[0], v[1]);
  uint32 hi = pk2(v[2], v[3]);
  *(u32x2*)(T1sT + (size_t)f*4096 + e0) = u32x2{lo, hi};
}

// ---------------- fin: out[n][f] = relu(dvs[n] * (P0+P1)[n][f]); dvs inline from dvpart ----------------
__global__ void fin_kernel(const unsigned short* __restrict__ P0, const unsigned short* __restrict__ P1,
                           const float* __restrict__ dvpart, float* __restrict__ out){
  int gid = blockIdx.x*256 + threadIdx.x;
  int n = gid >> 5;
  int f0 = (gid & 31) * 8;
  size_t off = (size_t)n*256 + f0;
  u32x4 a = *(const u32x4*)(P0 + off);
  u32x4 b = *(const u32x4*)(P1 + off);
  float s = dvpart[n] + dvpart[16384 + n] + dvpart[2*16384 + n] + dvpart[3*16384 + n];
  float d = rsqrtf(s + EPSC);
  f32x4_t o1, o2;
  #pragma unroll
  for (int j = 0; j < 4; ++j){
    float alo = __builtin_bit_cast(float, a[j] << 16);
    float ahi = __builtin_bit_cast(float, a[j] & 0xFFFF0000u);
    float blo = __builtin_bit_cast(float, b[j] << 16);
    float bhi = __builtin_bit_cast(float, b[j] & 0xFFFF0000u);
    float lo = fmaxf((alo + blo) * d, 0.f);
    float hi = fmaxf((ahi + bhi) * d, 0.f);
    if (j < 2){ o1[2*j] = lo; o1[2*j + 1] = hi; }
    else      { o2[2*(j-2)] = lo; o2[2*(j-2) + 1] = hi; }
  }
  *(f32x4_t*)(out + off) = o1;
  *(f32x4_t*)(out + off + 4) = o2;
}

extern "C" void kernel_launch(void* const* d_in, const int* in_sizes, int n_in,
                              void* d_out, int out_size, void* d_ws, size_t ws_size,
                              hipStream_t stream) {
  const float* emb = (const float*)d_in[0];   // [16384,256]
  const float* H   = (const float*)d_in[1];   // [16384,4096]
  const float* W   = (const float*)d_in[2];   // [256,256]
  float* out = (float*)d_out;                 // f32 [16384,256]

  char* ws = (char*)d_ws;
  unsigned short* WT        = (unsigned short*)(ws + 0);         //  131072 B
  unsigned short* XsT       = (unsigned short*)(ws + 131072);    // 8388608 B  [256][16384] bf16
  unsigned short* T1sT      = (unsigned short*)(ws + 8519680);   // 2097152 B  [256][4096] bf16
  unsigned short* Hb        = (unsigned short*)(ws + 10616832);  // 134217728 B [16384][4096] bf16
  unsigned short* T1p16     = (unsigned short*)(ws + 144834560); // 16777216 B [8][4096][256] bf16
  unsigned short* Op16      = (unsigned short*)(ws + 161611776); // 16777216 B [2][16384][256] bf16
  float*          departial = (float*)(ws + 178388992);          // 4194304 B [256][4096]
  float*          dvpart    = (float*)(ws + 182583296);          // 262144 B [4][16384]
  // total ws usage: 182,845,440 B

  // single streaming pass over H: Hb + degree partials; blocks 1024..1279 build WT
  hdeg_kernel<<<1280, 256, 0, stream>>>(H, dvpart, departial, Hb, W, WT);

  // X: XsT[f][n] = bf16(dvs[n] * (emb@W)[n][f]);  M=16384, K=256  (dvs from dvpart in-block)
  gemm_x<256, 256, 256, 256><<<256, 256, 0, stream>>>(emb, WT, dvpart, XsT);

  // GEMM1: T1p16[s][e][f];  M=4096 (e), K=16384 (n), split-K=8
  gemm_h<1, 4096, 16384, 32, 2048><<<256, 512, 0, stream>>>(Hb, XsT, T1p16);

  // T1s = De^-1 * sum(T1p16), bf16 transposed  (de from departial in-block)
  mid_kernel<<<1024, 256, 0, stream>>>(T1p16, departial, T1sT);

  // GEMM2: Op16[s][n][f];  M=16384 (n), K=4096 (e), split-K=2
  gemm_h<0, 4096, 4096, 128, 2048><<<256, 512, 0, stream>>>(Hb, T1sT, Op16);

  // out = relu(dvs[n] * (Op16_0 + Op16_1))  (dvs from dvpart inline)
  fin_kernel<<<2048, 256, 0, stream>>>(Op16, Op16 + (size_t)16384*256, dvpart, out);
}

// Round 17
// 204.520 us; speedup vs baseline: 1.5215x; 1.0106x over previous
//
#include <hip/hip_runtime.h>
#include <hip/hip_bf16.h>
#include <stdint.h>

typedef __attribute__((ext_vector_type(8))) __bf16 bf16x8;
typedef __attribute__((ext_vector_type(4))) float f32x4_t;
typedef __attribute__((ext_vector_type(2))) unsigned int u32x2;
typedef __attribute__((ext_vector_type(4))) unsigned int u32x4;
typedef unsigned int uint32;

#define EPSC 1e-6f

__device__ __forceinline__ unsigned short f2bf(float x){
  return __builtin_bit_cast(unsigned short, (__bf16)x);
}
__device__ __forceinline__ uint32 pk2(float a, float b){
  return (uint32)f2bf(a) | ((uint32)f2bf(b) << 16);
}
__device__ __forceinline__ float bfu2f(unsigned short u){
  return __builtin_bit_cast(float, ((uint32)u) << 16);
}

// ---------------- hdeg + prep: streaming H pass -> Hb bf16, degree partials; blocks >=1024 do WT ----------------
// grid 1280: blocks 0..1023 = (rb 0..255) x (cb 0..3), 64 rows x 1024 cols each; blocks 1024..1279: WT[f][c]=bf16(W[c][f])
__global__ __launch_bounds__(256, 4)
void hdeg_kernel(const float* __restrict__ H, float* __restrict__ dvpart,
                 float* __restrict__ departial, unsigned short* __restrict__ Hb,
                 const float* __restrict__ W, unsigned short* __restrict__ WT){
  __shared__ float wavepart[64][4];
  const int t = threadIdx.x;
  if (blockIdx.x >= 1024){
    int c = blockIdx.x - 1024;   // 0..255
    WT[(size_t)t*256 + c] = f2bf(W[(size_t)c*256 + t]);
    return;
  }
  const int lane = t & 63;
  const int w = t >> 6;
  const int rb = blockIdx.x & 255;
  const int cb = blockIdx.x >> 8;
  const size_t colbase = (size_t)cb*1024 + t*4;
  f32x4_t dacc = {0.f, 0.f, 0.f, 0.f};
  #pragma unroll 4
  for (int r = 0; r < 64; ++r){
    const int n = rb*64 + r;
    f32x4_t v = *(const f32x4_t*)(H + (size_t)n*4096 + colbase);
    dacc[0] += v[0]; dacc[1] += v[1]; dacc[2] += v[2]; dacc[3] += v[3];
    *(u32x2*)(Hb + (size_t)n*4096 + colbase) = u32x2{pk2(v[0], v[1]), pk2(v[2], v[3])};
    float rs = (v[0] + v[1]) + (v[2] + v[3]);
    #pragma unroll
    for (int d = 1; d < 64; d <<= 1) rs += __shfl_xor(rs, d);
    if (lane == 0) wavepart[r][w] = rs;
  }
  *(f32x4_t*)(departial + (size_t)rb*4096 + cb*1024 + t*4) = dacc;
  __syncthreads();
  if (t < 64){
    float s = wavepart[t][0] + wavepart[t][1] + wavepart[t][2] + wavepart[t][3];
    dvpart[(size_t)cb*16384 + rb*64 + t] = s;
  }
}

// ---------------- small MFMA GEMM (X = emb@W path); dvs computed in-block from dvpart ----------------
template<int LDA, int KB, int NMT, int CHUNK>
__global__ __launch_bounds__(256, 2)
void gemm_x(const float* __restrict__ Af, const unsigned short* __restrict__ BT,
            const float* __restrict__ dvpart, unsigned short* __restrict__ XsT)
{
  constexpr int NIT = CHUNK / 32;
  constexpr int ASZ = 64*32*2;
  constexpr int BSZ = 256*32*2;
  __shared__ __align__(16) char lds[2*ASZ + 2*BSZ];
  __shared__ float dvls[64];

  const int t = threadIdx.x;
  const int lane = t & 63;
  const int w = t >> 6;
  const int mt = blockIdx.x % NMT;
  const int s  = blockIdx.x / NMT;
  const int k0 = s * CHUNK;

  const int st_r  = t >> 2, st_cq = t & 3;

  f32x4_t acc[4][4] = {};
  f32x4_t pa[2];

  auto loadA = [&](int it){
    const float* p = Af + (size_t)(mt*64 + st_r)*LDA + k0 + it*32 + st_cq*4;
    pa[0] = *(const f32x4_t*)(p);
    pa[1] = *(const f32x4_t*)(p + 16);
  };

  auto gllB = [&](int it, int buf){
    char* bb = lds + 2*ASZ + buf*BSZ;
    const int kcur = k0 + it*32;
    const int swzh = ((lane & 3) ^ ((lane >> 2) & 3)) << 3;
    #pragma unroll
    for (int j = 0; j < 4; ++j){
      int chunk = w*4 + j;
      int frow = chunk*16 + (lane >> 2);
      const unsigned short* src = BT + (size_t)frow*KB + kcur + swzh;
      __builtin_amdgcn_global_load_lds((const __attribute__((address_space(1))) void*)src,
                                       (__attribute__((address_space(3))) void*)(bb + chunk*1024),
                                       16, 0, 0);
    }
  };

  auto stageA = [&](int buf){
    char* ab = lds + buf*ASZ;
    #pragma unroll
    for (int i = 0; i < 2; ++i){
      int f4 = st_cq + 4*i;
      uint32 lo = pk2(pa[i][0], pa[i][1]);
      uint32 hi = pk2(pa[i][2], pa[i][3]);
      *(u32x2*)(ab + st_r*64 + ((f4*8) ^ ((st_r & 3) << 4))) = u32x2{lo, hi};
    }
  };

  auto compute = [&](int buf){
    const char* ab = lds + buf*ASZ;
    const char* bb = lds + 2*ASZ + buf*BSZ;
    const int kswz = (((lane >> 4) ^ (lane & 3)) << 4);
    bf16x8 af[4], bfr[4];
    #pragma unroll
    for (int mi = 0; mi < 4; ++mi){
      int row = mi*16 + (lane & 15);
      af[mi] = *(const bf16x8*)(ab + row*64 + kswz);
    }
    #pragma unroll
    for (int fi = 0; fi < 4; ++fi){
      int row = w*64 + fi*16 + (lane & 15);
      bfr[fi] = *(const bf16x8*)(bb + row*64 + kswz);
    }
    #pragma unroll
    for (int mi = 0; mi < 4; ++mi){
      #pragma unroll
      for (int fi = 0; fi < 4; ++fi){
        acc[mi][fi] = __builtin_amdgcn_mfma_f32_16x16x32_bf16(af[mi], bfr[fi], acc[mi][fi], 0, 0, 0);
      }
    }
  };

  // block-local dvs (same add order as old finish_deg -> bit-identical)
  if (t < 64){
    int n = mt*64 + t;
    float s0 = dvpart[n] + dvpart[16384 + n] + dvpart[2*16384 + n] + dvpart[3*16384 + n];
    dvls[t] = rsqrtf(s0 + EPSC);
  }

  loadA(0);
  gllB(0, 0);
  stageA(0);
  __syncthreads();

  int cur = 0;
  #pragma unroll 1
  for (int it = 0; it < NIT; ++it){
    if (it + 1 < NIT){
      loadA(it + 1);
      gllB(it + 1, cur ^ 1);
    }
    compute(cur);
    if (it + 1 < NIT) stageA(cur ^ 1);
    __syncthreads();
    cur ^= 1;
  }

  #pragma unroll
  for (int mi = 0; mi < 4; ++mi){
    int l0 = mi*16 + ((lane >> 4) * 4);
    int n0 = mt*64 + l0;
    float d0 = dvls[l0], d1 = dvls[l0+1], d2 = dvls[l0+2], d3 = dvls[l0+3];
    #pragma unroll
    for (int fi = 0; fi < 4; ++fi){
      int f = w*64 + fi*16 + (lane & 15);
      uint32 lo = pk2(acc[mi][fi][0]*d0, acc[mi][fi][1]*d1);
      uint32 hi = pk2(acc[mi][fi][2]*d2, acc[mi][fi][3]*d3);
      *(u32x2*)(XsT + (size_t)f*16384 + n0) = u32x2{lo, hi};
    }
  }
}

// ---------------- big MFMA GEMM BM=128 x BN=256, 512 thr ----------------
// BK=64 phases, 3-tile LDS pipeline, issue-2-tiles-ahead, counted vmcnt(6), bf16 partial output.
// R17: deepened XOR swizzle (adds one row-octave term) -> 4-way ds_read bank conflicts become 2-way (free).
template<int TRANS, int LDA, int KB, int NMT, int CHUNK>
__global__ __launch_bounds__(512, 1)
void gemm_h(const unsigned short* __restrict__ Ah, const unsigned short* __restrict__ BT,
            unsigned short* __restrict__ Cp)
{
  constexpr int NIT = CHUNK / 32;   // slices
  constexpr int NT  = NIT / 2;      // BK=64 tiles
  static_assert(NT % 2 == 0 && NT >= 4, "tail/unroll assumptions");
  constexpr int ASLICE = 128*32*2;
  constexpr int BSLICE = 256*32*2;
  constexpr int ATILE = 2*ASLICE;
  constexpr int BTILE = 2*BSLICE;
  __shared__ __align__(16) char lds[3*ATILE + 3*BTILE];  // 147456 B

  const int t = threadIdx.x;
  const int lane = t & 63;
  const int w = t >> 6;
  const int wm = w >> 2;
  const int wf = w & 3;
  const int mt = blockIdx.x % NMT;
  const int s  = blockIdx.x / NMT;
  const int k0 = s * CHUNK;

  f32x4_t acc[4][4] = {};

  auto abase = [&](int sl){ return ((sl >> 1) % 3)*ATILE + (sl & 1)*ASLICE; };
  auto bbase = [&](int sl){ return 3*ATILE + ((sl >> 1) % 3)*BTILE + (sl & 1)*BSLICE; };

  auto gllB = [&](int sl){
    char* bb = lds + bbase(sl);
    const int kcur = k0 + sl*32;
    const int swzh = ((lane & 3) ^ ((lane >> 2) & 3) ^ ((lane >> 4) & 3)) << 3;  // +row-octave term
    #pragma unroll
    for (int j = 0; j < 2; ++j){
      int chunk = w*2 + j;
      int frow = chunk*16 + (lane >> 2);
      const unsigned short* src = BT + (size_t)frow*KB + kcur + swzh;
      __builtin_amdgcn_global_load_lds((const __attribute__((address_space(1))) void*)src,
                                       (__attribute__((address_space(3))) void*)(bb + chunk*1024),
                                       16, 0, 0);
    }
  };

  auto gllA = [&](int sl){
    char* ab = lds + abase(sl);
    const int kcur = k0 + sl*32;
    const int arow = lane >> 2;
    const int kqs  = (lane & 3) ^ (arow & 3) ^ ((arow >> 2) & 3);               // +row-octave term
    const unsigned short* src = Ah + (size_t)(mt*128 + w*16 + arow)*LDA + kcur + kqs*8;
    __builtin_amdgcn_global_load_lds((const __attribute__((address_space(1))) void*)src,
                                     (__attribute__((address_space(3))) void*)(ab + w*1024),
                                     16, 0, 0);
  };

  auto loadA_tr = [&](int sl) -> u32x4 {
    return *(const u32x4*)(Ah + (size_t)(k0 + sl*32 + (t >> 4))*LDA + mt*128 + (t & 15)*8);
  };

  auto stageA_tr = [&](int sl, u32x4 paw){
    char* ab = lds + abase(sl);
    const int n = t >> 4;
    const int trq = t & 15;
    const bool odd = n & 1;
    const int np = n >> 1;
    uint32 pw[4];
    #pragma unroll
    for (int j = 0; j < 4; ++j) pw[j] = (uint32)__shfl_xor((int)paw[j], 16);
    #pragma unroll
    for (int j = 0; j < 4; ++j){
      int e = trq*8 + 2*j + (odd ? 1 : 0);
      uint32 word = odd ? ((pw[j] >> 16)      | (paw[j] & 0xFFFF0000u))
                        : ((paw[j] & 0xFFFFu) | (pw[j] << 16));
      int pq = (np >> 2) ^ (trq & 3) ^ j;    // ^j == ^((e>>1)&3): uniform per j, fixes read conflicts
      *(uint32*)(ab + e*64 + pq*16 + (np & 3)*4) = word;
    }
  };

  auto compute = [&](int sl){
    const char* ab = lds + abase(sl);
    const char* bb = lds + bbase(sl);
    const int l15 = lane & 15;
    const int kq = lane >> 4;
    bf16x8 af[4], bfr[4];
    #pragma unroll
    for (int mi = 0; mi < 4; ++mi){
      int row = wm*64 + mi*16 + l15;
      int q = TRANS ? (kq ^ ((row >> 3) & 3) ^ ((row >> 1) & 3))
                    : (kq ^ (row & 3) ^ ((row >> 2) & 3));
      af[mi] = *(const bf16x8*)(ab + row*64 + q*16);
    }
    #pragma unroll
    for (int fi = 0; fi < 4; ++fi){
      int row = wf*64 + fi*16 + l15;
      bfr[fi] = *(const bf16x8*)(bb + row*64 + ((kq ^ (row & 3) ^ ((row >> 2) & 3)) << 4));
    }
    #pragma unroll
    for (int mi = 0; mi < 4; ++mi){
      #pragma unroll
      for (int fi = 0; fi < 4; ++fi){
        acc[mi][fi] = __builtin_amdgcn_mfma_f32_16x16x32_bf16(af[mi], bfr[fi], acc[mi][fi], 0, 0, 0);
      }
    }
  };

  if (TRANS){
    u32x4 e0, e1, o0, o1;
    e0 = loadA_tr(0); e1 = loadA_tr(1); gllB(0); gllB(1);
    o0 = loadA_tr(2); o1 = loadA_tr(3); gllB(2); gllB(3);
    stageA_tr(0, e0); stageA_tr(1, e1);
    asm volatile("s_waitcnt vmcnt(6) lgkmcnt(0)" ::: "memory");
    __builtin_amdgcn_s_barrier();

    #pragma unroll 1
    for (int T = 0; T < NT - 2; T += 2){
      e0 = loadA_tr(2*T + 4); e1 = loadA_tr(2*T + 5);
      gllB(2*T + 4); gllB(2*T + 5);
      compute(2*T); compute(2*T + 1);
      stageA_tr(2*T + 2, o0); stageA_tr(2*T + 3, o1);
      asm volatile("s_waitcnt vmcnt(6) lgkmcnt(0)" ::: "memory");
      __builtin_amdgcn_s_barrier();
      o0 = loadA_tr(2*T + 6); o1 = loadA_tr(2*T + 7);
      gllB(2*T + 6); gllB(2*T + 7);
      compute(2*T + 2); compute(2*T + 3);
      stageA_tr(2*T + 4, e0); stageA_tr(2*T + 5, e1);
      asm volatile("s_waitcnt vmcnt(6) lgkmcnt(0)" ::: "memory");
      __builtin_amdgcn_s_barrier();
    }
    compute(2*NT - 4); compute(2*NT - 3);
    stageA_tr(2*NT - 2, o0); stageA_tr(2*NT - 1, o1);
    asm volatile("s_waitcnt vmcnt(0) lgkmcnt(0)" ::: "memory");
    __builtin_amdgcn_s_barrier();
    compute(2*NT - 2); compute(2*NT - 1);
  } else {
    gllB(0); gllA(0); gllB(1); gllA(1);
    gllB(2); gllA(2); gllB(3); gllA(3);
    asm volatile("s_waitcnt vmcnt(6)" ::: "memory");
    __builtin_amdgcn_s_barrier();

    #pragma unroll 1
    for (int T = 0; T < NT - 2; ++T){
      gllB(2*T + 4); gllA(2*T + 4); gllB(2*T + 5); gllA(2*T + 5);
      compute(2*T); compute(2*T + 1);
      asm volatile("s_waitcnt vmcnt(6)" ::: "memory");
      __builtin_amdgcn_s_barrier();
    }
    compute(2*NT - 4); compute(2*NT - 3);
    asm volatile("s_waitcnt vmcnt(0)" ::: "memory");
    __builtin_amdgcn_s_barrier();
    compute(2*NT - 2); compute(2*NT - 1);
  }

  unsigned short* C = Cp + (size_t)s * (NMT*128) * 256;
  #pragma unroll
  for (int mi = 0; mi < 4; ++mi){
    int row0 = mt*128 + wm*64 + mi*16 + ((lane >> 4) * 4);
    #pragma unroll
    for (int fi = 0; fi < 4; ++fi){
      int f = wf*64 + fi*16 + (lane & 15);
      #pragma unroll
      for (int r = 0; r < 4; ++r)
        C[(size_t)(row0 + r)*256 + f] = f2bf(acc[mi][fi][r]);
    }
  }
}

// ---------------- mid: de computed in-block from departial (finish_deg's exact add order) ----------------
__global__ void mid_kernel(const unsigned short* __restrict__ T1p, const float* __restrict__ departial,
                           unsigned short* __restrict__ T1sT){
  __shared__ float sm[4][4];       // [r][part]
  __shared__ float de_local[4];
  int t = threadIdx.x;
  int e0 = blockIdx.x * 4;
  if (t < 16){
    int r = t & 3, part = t >> 2;
    float s = 0.f;
    #pragma unroll 4
    for (int i = 0; i < 64; ++i)
      s += departial[(size_t)(part*64 + i)*4096 + e0 + r];
    sm[r][part] = s;
  }
  __syncthreads();
  if (t < 4) de_local[t] = sm[t][0] + sm[t][1] + sm[t][2] + sm[t][3];
  __syncthreads();
  int f = t;
  float v[4];
  #pragma unroll
  for (int r = 0; r < 4; ++r){
    float acc = 0.f;
    #pragma unroll
    for (int s = 0; s < 8; ++s)
      acc += bfu2f(T1p[(size_t)s*4096*256 + (size_t)(e0 + r)*256 + f]);
    v[r] = acc / (de_local[r] + EPSC);
  }
  uint32 lo = pk2(v[0], v[1]);
  uint32 hi = pk2(v[2], v[3]);
  *(u32x2*)(T1sT + (size_t)f*4096 + e0) = u32x2{lo, hi};
}

// ---------------- fin: out[n][f] = relu(dvs[n] * (P0+P1)[n][f]); dvs inline from dvpart ----------------
__global__ void fin_kernel(const unsigned short* __restrict__ P0, const unsigned short* __restrict__ P1,
                           const float* __restrict__ dvpart, float* __restrict__ out){
  int gid = blockIdx.x*256 + threadIdx.x;
  int n = gid >> 5;
  int f0 = (gid & 31) * 8;
  size_t off = (size_t)n*256 + f0;
  u32x4 a = *(const u32x4*)(P0 + off);
  u32x4 b = *(const u32x4*)(P1 + off);
  float s = dvpart[n] + dvpart[16384 + n] + dvpart[2*16384 + n] + dvpart[3*16384 + n];
  float d = rsqrtf(s + EPSC);
  f32x4_t o1, o2;
  #pragma unroll
  for (int j = 0; j < 4; ++j){
    float alo = __builtin_bit_cast(float, a[j] << 16);
    float ahi = __builtin_bit_cast(float, a[j] & 0xFFFF0000u);
    float blo = __builtin_bit_cast(float, b[j] << 16);
    float bhi = __builtin_bit_cast(float, b[j] & 0xFFFF0000u);
    float lo = fmaxf((alo + blo) * d, 0.f);
    float hi = fmaxf((ahi + bhi) * d, 0.f);
    if (j < 2){ o1[2*j] = lo; o1[2*j + 1] = hi; }
    else      { o2[2*(j-2)] = lo; o2[2*(j-2) + 1] = hi; }
  }
  *(f32x4_t*)(out + off) = o1;
  *(f32x4_t*)(out + off + 4) = o2;
}

extern "C" void kernel_launch(void* const* d_in, const int* in_sizes, int n_in,
                              void* d_out, int out_size, void* d_ws, size_t ws_size,
                              hipStream_t stream) {
  const float* emb = (const float*)d_in[0];   // [16384,256]
  const float* H   = (const float*)d_in[1];   // [16384,4096]
  const float* W   = (const float*)d_in[2];   // [256,256]
  float* out = (float*)d_out;                 // f32 [16384,256]

  char* ws = (char*)d_ws;
  unsigned short* WT        = (unsigned short*)(ws + 0);         //  131072 B
  unsigned short* XsT       = (unsigned short*)(ws + 131072);    // 8388608 B  [256][16384] bf16
  unsigned short* T1sT      = (unsigned short*)(ws + 8519680);   // 2097152 B  [256][4096] bf16
  unsigned short* Hb        = (unsigned short*)(ws + 10616832);  // 134217728 B [16384][4096] bf16
  unsigned short* T1p16     = (unsigned short*)(ws + 144834560); // 16777216 B [8][4096][256] bf16
  unsigned short* Op16      = (unsigned short*)(ws + 161611776); // 16777216 B [2][16384][256] bf16
  float*          departial = (float*)(ws + 178388992);          // 4194304 B [256][4096]
  float*          dvpart    = (float*)(ws + 182583296);          // 262144 B [4][16384]
  // total ws usage: 182,845,440 B

  // single streaming pass over H: Hb + degree partials; blocks 1024..1279 build WT
  hdeg_kernel<<<1280, 256, 0, stream>>>(H, dvpart, departial, Hb, W, WT);

  // X: XsT[f][n] = bf16(dvs[n] * (emb@W)[n][f]);  M=16384, K=256  (dvs from dvpart in-block)
  gemm_x<256, 256, 256, 256><<<256, 256, 0, stream>>>(emb, WT, dvpart, XsT);

  // GEMM1: T1p16[s][e][f];  M=4096 (e), K=16384 (n), split-K=8
  gemm_h<1, 4096, 16384, 32, 2048><<<256, 512, 0, stream>>>(Hb, XsT, T1p16);

  // T1s = De^-1 * sum(T1p16), bf16 transposed  (de from departial in-block)
  mid_kernel<<<1024, 256, 0, stream>>>(T1p16, departial, T1sT);

  // GEMM2: Op16[s][n][f];  M=16384 (n), K=4096 (e), split-K=2
  gemm_h<0, 4096, 4096, 128, 2048><<<256, 512, 0, stream>>>(Hb, T1sT, Op16);

  // out = relu(dvs[n] * (Op16_0 + Op16_1))  (dvs from dvpart inline)
  fin_kernel<<<2048, 256, 0, stream>>>(Op16, Op16 + (size_t)16384*256, dvpart, out);
}